// Round 5
// baseline (324.580 us; speedup 1.0000x reference)
//
#include <hip/hip_runtime.h>
#include <hip/hip_bf16.h>

#define Bn 1024
#define Lr 320
#define Dd 128
#define Ee 8
#define Pp 96

typedef short bf16x8 __attribute__((ext_vector_type(8)));
typedef float f32x4 __attribute__((ext_vector_type(4)));
typedef unsigned u32x4 __attribute__((ext_vector_type(4)));
typedef unsigned short u16;

__device__ __forceinline__ float cdf_f(float v) {
    return 0.5f * (1.0f + erff(v * 0.70710678118654752f));
}
__device__ __forceinline__ float softplus_f(float x) {
    return fmaxf(x, 0.0f) + log1pf(expf(-fabsf(x)));
}
__device__ __forceinline__ u16 f2bf(float f) {
    unsigned int u = __float_as_uint(f);
    return (u16)((u + 0x7fffu + ((u >> 16) & 1u)) >> 16);
}
__device__ __forceinline__ float bf2f(u16 u) {
    return __uint_as_float(((unsigned int)u) << 16);
}

// async global->LDS, 16 B per lane; LDS dest is wave-uniform base + lane*16.
__device__ __forceinline__ void gload16(const void* g, void* l) {
    __builtin_amdgcn_global_load_lds(
        (const __attribute__((address_space(1))) void*)g,
        (__attribute__((address_space(3))) void*)l, 16, 0, 0);
}

// expert_w fp32 [e][l][p] -> W_t bf16 [e][p][l] (l contiguous). 0.5 MB, L2-resident.
// Block (0,0) also zeroes accum (replaces the hipMemsetAsync dispatch; stream
// order guarantees it completes before gg_kernel's atomics).
__global__ __launch_bounds__(256) void transpose_w(
    const float* __restrict__ ew, u16* __restrict__ wt,
    float* __restrict__ accum)
{
    __shared__ float tile[Pp * 33];
    const int e  = blockIdx.x;       // 0..7
    const int l0 = blockIdx.y * 32;  // 0..288
    const int t  = threadIdx.x;
    if (e == 0 && blockIdx.y == 0 && t < 16) accum[t] = 0.f;
    #pragma unroll
    for (int i = 0; i < 12; ++i) {
        const int idx = t + 256 * i;            // 0..3071
        const int lp = idx / 96, p = idx - 96 * lp;
        tile[p * 33 + lp] = ew[((size_t)e * Lr + l0 + lp) * Pp + p];
    }
    __syncthreads();
    #pragma unroll
    for (int i = 0; i < 6; ++i) {
        const int g = t + 256 * i;              // 0..1535
        const int p = g >> 4, l2 = (g & 15) * 2;
        const unsigned pk = (unsigned)f2bf(tile[p * 33 + l2]) |
                            ((unsigned)f2bf(tile[p * 33 + l2 + 1]) << 16);
        *(unsigned*)&wt[((size_t)(e * Pp + p)) * Lr + l0 + l2] = pk;
    }
}

// Fused g+gate: one 256-thread block per b at 8 blocks/CU (full streaming
// occupancy, ~1.4 KB LDS). Computes g[b,:] into LDS with FP order identical
// to the old g_kernel (f8-octant float4 dot + 8-lane shfl tree; lc is just
// moved to an inner loop), then wave 0 runs the old gate_kernel code against
// LDS g. Eliminates the gbuf HBM round-trip and the gate dispatch.
__global__ __launch_bounds__(256, 8) void gg_kernel(
    const float* __restrict__ x, const float* __restrict__ start_w,
    const float* __restrict__ start_b, const float* __restrict__ noise,
    const float* __restrict__ w_gate, const float* __restrict__ w_noise,
    float* __restrict__ accum, float* __restrict__ gates_out)
{
    __shared__ float gl[Lr];
    const int t = threadIdx.x;
    const int b = blockIdx.x;
    const float sb = start_b[0];
    const int f8 = t & 7;

    float4 sw[4];
    #pragma unroll
    for (int j = 0; j < 4; ++j) sw[j] = ((const float4*)start_w)[f8 + 8 * j];

    const float* xb = x + (size_t)b * Lr * Dd;
    #pragma unroll
    for (int lc = 0; lc < 5; ++lc) {
        #pragma unroll
        for (int p2 = 0; p2 < 2; ++p2) {
            const int r = lc * 64 + p2 * 32 + (t >> 3);
            float acc = 0.f;
            #pragma unroll
            for (int j = 0; j < 4; ++j) {
                const float4 v = ((const float4*)(xb + (size_t)r * Dd))[f8 + 8 * j];
                acc += v.x * sw[j].x + v.y * sw[j].y + v.z * sw[j].z + v.w * sw[j].w;
            }
            #pragma unroll
            for (int off = 1; off <= 4; off <<= 1) acc += __shfl_xor(acc, off);
            if (f8 == 0) gl[r] = acc + sb;
        }
    }
    __syncthreads();

    // gate (wave 0 only; code == old gate_kernel, g read from LDS)
    if (t < 64) {
        const int e = t & 7, seg = t >> 3;
        float pc = 0.f, pn = 0.f;
        #pragma unroll 8
        for (int i = 0; i < 40; ++i) {
            const int l = seg * 40 + i;
            const float gv = gl[l];
            pc += gv * w_gate[l * Ee + e];
            pn += gv * w_noise[l * Ee + e];
        }
        #pragma unroll
        for (int off = 8; off <= 32; off <<= 1) {
            pc += __shfl_xor(pc, off);
            pn += __shfl_xor(pn, off);
        }
        const float sdv   = softplus_f(pn) + 0.01f;   // NOISE_EPS
        float       c     = pc;
        const float nz    = noise[b * Ee + e];
        const float noisy = c + nz * sdv;

        float nv[8];
        #pragma unroll
        for (int j = 0; j < 8; ++j) nv[j] = __shfl(noisy, j);

        int i0 = -1, i1 = -1;
        float v0 = -INFINITY, v1 = -INFINITY, v2 = -INFINITY;
        #pragma unroll
        for (int i = 0; i < 8; ++i) if (nv[i] > v0) { v0 = nv[i]; i0 = i; }
        #pragma unroll
        for (int i = 0; i < 8; ++i) if (i != i0 && nv[i] > v1) { v1 = nv[i]; i1 = i; }
        #pragma unroll
        for (int i = 0; i < 8; ++i) if (i != i0 && i != i1 && nv[i] > v2) { v2 = nv[i]; }

        const float ex1 = expf(v1 - v0);
        const float den = 1.f + ex1;
        const float gate_e = (e == i0) ? (1.f / den) : ((e == i1) ? (ex1 / den) : 0.f);

        if (isnan(c)) c = 0.f;
        const float pr = (noisy > v2) ? cdf_f((c - v2) / sdv) : cdf_f((c - v1) / sdv);

        if (t < 8) {
            gates_out[b * Ee + e] = gate_e;
            atomicAdd(&accum[8 + e], gate_e);  // importance
            atomicAdd(&accum[e], pr);          // load
        }
    }
}

// K2 (round-3 verified, unchanged): per K-tile (32 l) stage x (fp32 [32][64])
// and both experts' raw bf16 W tiles via async global_load_lds dwordx4,
// double-buffered, one barrier per tile. Source-side XOR swizzle keeps W
// ds_read_b128 conflict-free and x ds_read_b32 2-way (free). Dual
// accumulators; fp32 combine with gates in the epilogue.
// grid 2048 = (b, d-half), 4 waves = 4 n-tiles of 16 d. LDS 40 KB -> 4 blk/CU.
__global__ __launch_bounds__(256, 4) void mm_kernel(
    const float* __restrict__ x, const u16* __restrict__ wt,
    const float* __restrict__ expert_b, const float* __restrict__ gates,
    float* __restrict__ out)
{
    __shared__ __align__(16) float    Xs[2][32 * 64];    // 16 KB
    __shared__ __align__(16) unsigned Ws[2][192 * 16];   // 24 KB

    const int b    = blockIdx.x >> 1;
    const int h    = blockIdx.x & 1;              // d-half
    const int tid  = threadIdx.x;
    const int lane = tid & 63;
    const int wv   = tid >> 6;                    // wave = n-tile (16 d)
    const int quad = lane >> 4;
    const int r16  = lane & 15;

    // top-2 experts (gates has exactly 2 nonzeros per b)
    int e0 = 0, e1 = 0; float g0 = 0.f, g1 = 0.f; int cnt = 0;
    #pragma unroll
    for (int e = 0; e < Ee; ++e) {
        const float gv = gates[b * Ee + e];
        if (gv != 0.f) {
            if (cnt == 0) { e0 = e; g0 = gv; }
            else if (cnt == 1) { e1 = e; g1 = gv; }
            ++cnt;
        }
    }

    const float* xb  = x + (size_t)b * Lr * Dd + h * 64;
    const u16*   w0r = wt + (size_t)e0 * Pp * Lr;
    const u16*   w1r = wt + (size_t)e1 * Pp * Lr;

    // staging lane constants
    const int xrow = lane >> 4;      // row within 4-row x chunk
    const int xcol = lane & 15;      // 16B-quad within x row
    const int wrow = lane >> 2;      // row within 16-row W chunk
    const int wq   = lane & 3;       // 16B-quad within W row

    auto STAGE = [&](int buf, int l0) {
        // x: 8 chunks of 1 KB (4 rows each); wave wv stages chunks 2wv,2wv+1
        #pragma unroll
        for (int i = 0; i < 2; ++i) {
            const int c  = 2 * wv + i;
            const int l  = 4 * c + xrow;                       // 0..31
            const int sx = (((l >> 3) & 1) << 4) | (((l >> 3) & 2) << 1);
            const int d4 = (4 * xcol) ^ sx;                    // swizzled src dword
            gload16(xb + (size_t)(l0 + l) * Dd + d4, (void*)&Xs[buf][c * 256]);
        }
        // W: 12 chunks of 1 KB (16 rows each); rows 0..95 = e0, 96..191 = e1
        #pragma unroll
        for (int i = 0; i < 3; ++i) {
            const int c  = 3 * wv + i;
            const int r  = 16 * c + wrow;                      // 0..191
            const int dw = (4 * wq) ^ ((r & 3) << 2);          // swizzled src dword
            const u16* src = (c < 6) ? (w0r + (size_t)r * Lr)
                                     : (w1r + (size_t)(r - 96) * Lr);
            gload16(src + l0 + 2 * dw, (void*)&Ws[buf][c * 256]);
        }
    };

    f32x4 a0[6], a1[6];
    #pragma unroll
    for (int m = 0; m < 6; ++m) {
        a0[m] = (f32x4){0.f, 0.f, 0.f, 0.f};
        a1[m] = (f32x4){0.f, 0.f, 0.f, 0.f};
    }

    // read-side lane constants (match staging swizzles)
    const int sxq    = ((quad & 1) << 4) | ((quad & 2) << 1); // x swizzle (l-quad)
    const int xcolr  = (16 * wv + r16) ^ sxq;                 // swizzled x dword-in-row
    const int wdw    = (4 * quad) ^ ((r16 & 3) << 2);         // swizzled W dword base

    union UF { u32x4 q; bf16x8 v; unsigned u[4]; };

    STAGE(0, 0);
    __syncthreads();
    int cur = 0;
    for (int t = 0; t < 10; ++t) {
        if (t < 9) STAGE(cur ^ 1, 32 * (t + 1));
        // B fragment: x[l0+8q+k][d], k=0..7, from LDS fp32, pack to bf16
        float xv[8];
        #pragma unroll
        for (int k = 0; k < 8; ++k)
            xv[k] = Xs[cur][(8 * quad + k) * 64 + xcolr];
        UF xf;
        #pragma unroll
        for (int k2 = 0; k2 < 4; ++k2)
            xf.u[k2] = (unsigned)f2bf(xv[2 * k2]) |
                       ((unsigned)f2bf(xv[2 * k2 + 1]) << 16);
        // A fragments: one ds_read_b128 per (expert, m-tile), conflict-free
        #pragma unroll
        for (int m = 0; m < 6; ++m) {
            UF a0f, a1f;
            a0f.q = *(const u32x4*)&Ws[cur][(16 * m + r16) * 16 + wdw];
            a1f.q = *(const u32x4*)&Ws[cur][(96 + 16 * m + r16) * 16 + wdw];
            a0[m] = __builtin_amdgcn_mfma_f32_16x16x32_bf16(a0f.v, xf.v, a0[m], 0, 0, 0);
            a1[m] = __builtin_amdgcn_mfma_f32_16x16x32_bf16(a1f.v, xf.v, a1[m], 0, 0, 0);
        }
        __syncthreads();
        cur ^= 1;
    }

    // epilogue: fp32 combine + bias. C/D layout: col(d)=r16, row(p)=4*quad+reg
    const int d = h * 64 + 16 * wv + r16;
    const float* eb0 = expert_b + (size_t)e0 * Pp * Dd;
    const float* eb1 = expert_b + (size_t)e1 * Pp * Dd;
    #pragma unroll
    for (int m = 0; m < 6; ++m) {
        #pragma unroll
        for (int r = 0; r < 4; ++r) {
            const int p = 16 * m + 4 * quad + r;
            out[((size_t)b * Pp + p) * Dd + d] =
                g0 * (a0[m][r] + eb0[p * Dd + d]) +
                g1 * (a1[m][r] + eb1[p * Dd + d]);
        }
    }
}

__global__ void loss_kernel(const float* __restrict__ accum,
                            float* __restrict__ out_scalars)
{
    if (threadIdx.x == 0) {
        float lo[8], im[8];
        #pragma unroll
        for (int i = 0; i < 8; ++i) { lo[i] = accum[i]; im[i] = accum[8 + i]; }
        float ml = 0.f, mi = 0.f;
        #pragma unroll
        for (int i = 0; i < 8; ++i) { ml += lo[i]; mi += im[i]; }
        ml *= 0.125f; mi *= 0.125f;
        float sl = 0.f, si = 0.f;
        #pragma unroll
        for (int i = 0; i < 8; ++i) {
            const float dl = lo[i] - ml, di = im[i] - mi;
            sl += dl * dl; si += di * di;
        }
        const float cvl = (sl / 7.f) / (ml * ml + 1e-10f);
        const float cvi = (si / 7.f) / (mi * mi + 1e-10f);
        out_scalars[0] = 0.01f * (cvi + cvl);
        out_scalars[1] = 0.0f;
    }
}

extern "C" void kernel_launch(void* const* d_in, const int* in_sizes, int n_in,
                              void* d_out, int out_size, void* d_ws, size_t ws_size,
                              hipStream_t stream)
{
    const float* x        = (const float*)d_in[0];
    // d_in[1] = x_mark_enc (unused)
    const float* noise    = (const float*)d_in[2];
    const float* start_w  = (const float*)d_in[3];
    const float* start_b  = (const float*)d_in[4];
    const float* w_gate   = (const float*)d_in[5];
    const float* w_noise  = (const float*)d_in[6];
    const float* expert_w = (const float*)d_in[7];
    const float* expert_b = (const float*)d_in[8];
    float* out            = (float*)d_out;

    float* accum = (float*)d_ws;                 // 16 f
    float* gates = accum + 16;                   // 8192 f
    u16*   wt    = (u16*)(gates + Bn * Ee);      // 8*96*320 bf16

    hipLaunchKernelGGL(transpose_w, dim3(Ee, Lr / 32), dim3(256), 0, stream,
                       expert_w, wt, accum);
    hipLaunchKernelGGL(gg_kernel, dim3(Bn), dim3(256), 0, stream,
                       x, start_w, start_b, noise, w_gate, w_noise,
                       accum, gates);
    hipLaunchKernelGGL(mm_kernel, dim3(Bn * 2), dim3(256), 0, stream,
                       x, wt, expert_b, gates, out);
    hipLaunchKernelGGL(loss_kernel, dim3(1), dim3(64), 0, stream,
                       accum, out + (size_t)Bn * Pp * Dd);
}

// Round 6
// 304.786 us; speedup vs baseline: 1.0649x; 1.0649x over previous
//
#include <hip/hip_runtime.h>
#include <hip/hip_bf16.h>

#define Bn 1024
#define Lr 320
#define Dd 128
#define Ee 8
#define Pp 96

typedef short bf16x8 __attribute__((ext_vector_type(8)));
typedef float f32x4 __attribute__((ext_vector_type(4)));
typedef unsigned u32x4 __attribute__((ext_vector_type(4)));
typedef unsigned short u16;

__device__ __forceinline__ float cdf_f(float v) {
    return 0.5f * (1.0f + erff(v * 0.70710678118654752f));
}
__device__ __forceinline__ float softplus_f(float x) {
    return fmaxf(x, 0.0f) + log1pf(expf(-fabsf(x)));
}
__device__ __forceinline__ u16 f2bf(float f) {
    unsigned int u = __float_as_uint(f);
    return (u16)((u + 0x7fffu + ((u >> 16) & 1u)) >> 16);
}
__device__ __forceinline__ float bf2f(u16 u) {
    return __uint_as_float(((unsigned int)u) << 16);
}

// async global->LDS, 16 B per lane; LDS dest is wave-uniform base + lane*16.
__device__ __forceinline__ void gload16(const void* g, void* l) {
    __builtin_amdgcn_global_load_lds(
        (const __attribute__((address_space(1))) void*)g,
        (__attribute__((address_space(3))) void*)l, 16, 0, 0);
}

// expert_w fp32 [e][l][p] -> W_t bf16 [e][p][l] (l contiguous). 0.5 MB, L2-resident.
// Block (0,0) also zeroes accum (replaces the hipMemsetAsync dispatch).
__global__ __launch_bounds__(256) void transpose_w(
    const float* __restrict__ ew, u16* __restrict__ wt,
    float* __restrict__ accum)
{
    __shared__ float tile[Pp * 33];
    const int e  = blockIdx.x;       // 0..7
    const int l0 = blockIdx.y * 32;  // 0..288
    const int t  = threadIdx.x;
    if (e == 0 && blockIdx.y == 0 && t < 16) accum[t] = 0.f;
    #pragma unroll
    for (int i = 0; i < 12; ++i) {
        const int idx = t + 256 * i;            // 0..3071
        const int lp = idx / 96, p = idx - 96 * lp;
        tile[p * 33 + lp] = ew[((size_t)e * Lr + l0 + lp) * Pp + p];
    }
    __syncthreads();
    #pragma unroll
    for (int i = 0; i < 6; ++i) {
        const int g = t + 256 * i;              // 0..1535
        const int p = g >> 4, l2 = (g & 15) * 2;
        const unsigned pk = (unsigned)f2bf(tile[p * 33 + l2]) |
                            ((unsigned)f2bf(tile[p * 33 + l2 + 1]) << 16);
        *(unsigned*)&wt[((size_t)(e * Pp + p)) * Lr + l0 + l2] = pk;
    }
}

// K1a (R3-verified, unchanged): g[b,l] = dot(x[b,l,:], start_w) + sb.
__global__ __launch_bounds__(256, 8) void g_kernel(
    const float* __restrict__ x, const float* __restrict__ start_w,
    const float* __restrict__ start_b, float* __restrict__ g_out)
{
    const int t  = threadIdx.x;
    const int lc = blockIdx.x;       // 0..4
    const int b  = blockIdx.y;       // 0..1023
    const float sb = start_b[0];

    float4 sw[4];
    #pragma unroll
    for (int j = 0; j < 4; ++j) sw[j] = ((const float4*)start_w)[(t & 7) + 8 * j];

    const float* xb = x + ((size_t)b * Lr + lc * 64) * Dd;
    #pragma unroll
    for (int p2 = 0; p2 < 2; ++p2) {
        const int r = p2 * 32 + (t >> 3);
        float acc = 0.f;
        #pragma unroll
        for (int j = 0; j < 4; ++j) {
            const float4 v = ((const float4*)(xb + (size_t)r * Dd))[(t & 7) + 8 * j];
            acc += v.x * sw[j].x + v.y * sw[j].y + v.z * sw[j].z + v.w * sw[j].w;
        }
        #pragma unroll
        for (int off = 1; off <= 4; off <<= 1) acc += __shfl_xor(acc, off);
        if ((t & 7) == 0) g_out[(size_t)b * Lr + lc * 64 + r] = acc + sb;
    }
}

// K1b (R3-verified, unchanged): per-b logits, noisy top-3, gates, prob.
__global__ __launch_bounds__(256) void gate_kernel(
    const float* __restrict__ g, const float* __restrict__ noise,
    const float* __restrict__ w_gate, const float* __restrict__ w_noise,
    float* __restrict__ accum, float* __restrict__ gates_out)
{
    __shared__ float sred[16];
    const int t    = threadIdx.x;
    const int lane = t & 63;
    const int wv   = t >> 6;
    const int b    = blockIdx.x * 4 + wv;

    if (t < 16) sred[t] = 0.f;
    __syncthreads();

    const int e = lane & 7, seg = lane >> 3;
    const float* gb = g + (size_t)b * Lr;
    float pc = 0.f, pn = 0.f;
    #pragma unroll 8
    for (int i = 0; i < 40; ++i) {
        const int l = seg * 40 + i;
        const float gv = gb[l];
        pc += gv * w_gate[l * Ee + e];
        pn += gv * w_noise[l * Ee + e];
    }
    #pragma unroll
    for (int off = 8; off <= 32; off <<= 1) {
        pc += __shfl_xor(pc, off);
        pn += __shfl_xor(pn, off);
    }
    const float sdv   = softplus_f(pn) + 0.01f;   // NOISE_EPS
    float       c     = pc;
    const float nz    = noise[b * Ee + e];
    const float noisy = c + nz * sdv;

    float nv[8];
    #pragma unroll
    for (int j = 0; j < 8; ++j) nv[j] = __shfl(noisy, j);

    int i0 = -1, i1 = -1;
    float v0 = -INFINITY, v1 = -INFINITY, v2 = -INFINITY;
    #pragma unroll
    for (int i = 0; i < 8; ++i) if (nv[i] > v0) { v0 = nv[i]; i0 = i; }
    #pragma unroll
    for (int i = 0; i < 8; ++i) if (i != i0 && nv[i] > v1) { v1 = nv[i]; i1 = i; }
    #pragma unroll
    for (int i = 0; i < 8; ++i) if (i != i0 && i != i1 && nv[i] > v2) { v2 = nv[i]; }

    const float ex1 = expf(v1 - v0);
    const float den = 1.f + ex1;
    const float gate_e = (e == i0) ? (1.f / den) : ((e == i1) ? (ex1 / den) : 0.f);

    if (isnan(c)) c = 0.f;
    const float pr = (noisy > v2) ? cdf_f((c - v2) / sdv) : cdf_f((c - v1) / sdv);

    if (lane < 8) {
        gates_out[b * Ee + e] = gate_e;
        atomicAdd(&sred[8 + e], gate_e);  // importance
        atomicAdd(&sred[e], pr);          // load
    }
    __syncthreads();
    if (t < 16) atomicAdd(&accum[t], sred[t]);
}

// K2 v4: W dbuf in LDS (round-3-proven staging/swizzle verbatim, 24 KB);
// x fragments DIRECT from global (R1-proven gather: x is L2/L3-warm after
// g_kernel) into ping-pong register arrays with a manual 1-tile software
// pipeline. Barrier drains now wait only L2-latency loads issued a full
// compute-phase earlier. 11 VMEM instr/wave/tile. Block 0 also computes the
// loss (accum is final: gate_kernel completed). grid 2048 = (b, d-half).
__global__ __launch_bounds__(256, 4) void mm_kernel(
    const float* __restrict__ x, const u16* __restrict__ wt,
    const float* __restrict__ expert_b, const float* __restrict__ gates,
    const float* __restrict__ accum, float* __restrict__ out)
{
    __shared__ __align__(16) unsigned Ws[2][192 * 16];   // 24 KB

    const int tid  = threadIdx.x;

    // folded loss (runs while other blocks stage; accum final before launch)
    if (blockIdx.x == 0 && tid == 0) {
        float lo[8], im[8];
        #pragma unroll
        for (int i = 0; i < 8; ++i) { lo[i] = accum[i]; im[i] = accum[8 + i]; }
        float ml = 0.f, mi = 0.f;
        #pragma unroll
        for (int i = 0; i < 8; ++i) { ml += lo[i]; mi += im[i]; }
        ml *= 0.125f; mi *= 0.125f;
        float sl = 0.f, si = 0.f;
        #pragma unroll
        for (int i = 0; i < 8; ++i) {
            const float dl = lo[i] - ml, di = im[i] - mi;
            sl += dl * dl; si += di * di;
        }
        const float cvl = (sl / 7.f) / (ml * ml + 1e-10f);
        const float cvi = (si / 7.f) / (mi * mi + 1e-10f);
        float* os = out + (size_t)Bn * Pp * Dd;
        os[0] = 0.01f * (cvi + cvl);
        os[1] = 0.0f;
    }

    const int b    = blockIdx.x >> 1;
    const int h    = blockIdx.x & 1;              // d-half
    const int lane = tid & 63;
    const int wv   = tid >> 6;                    // wave = n-tile (16 d)
    const int quad = lane >> 4;
    const int r16  = lane & 15;

    // top-2 experts (gates has exactly 2 nonzeros per b)
    int e0 = 0, e1 = 0; float g0 = 0.f, g1 = 0.f; int cnt = 0;
    #pragma unroll
    for (int e = 0; e < Ee; ++e) {
        const float gv = gates[b * Ee + e];
        if (gv != 0.f) {
            if (cnt == 0) { e0 = e; g0 = gv; }
            else if (cnt == 1) { e1 = e; g1 = gv; }
            ++cnt;
        }
    }

    const u16* w0r = wt + (size_t)e0 * Pp * Lr;
    const u16* w1r = wt + (size_t)e1 * Pp * Lr;

    const int d = h * 64 + 16 * wv + r16;          // output column of this lane
    const float* xg = x + ((size_t)b * Lr + 8 * quad) * Dd + d;

    // W staging lane constants (round-3 scheme verbatim)
    const int wrow = lane >> 2;      // row within 16-row W chunk
    const int wq   = lane & 3;       // 16B-quad within W row

    auto STAGE_W = [&](int buf, int l0) {
        #pragma unroll
        for (int i = 0; i < 3; ++i) {
            const int c  = 3 * wv + i;                         // 0..11
            const int r  = 16 * c + wrow;                      // 0..191
            const int dw = (4 * wq) ^ ((r & 3) << 2);          // swizzled src dword
            const u16* src = (c < 6) ? (w0r + (size_t)r * Lr)
                                     : (w1r + (size_t)(r - 96) * Lr);
            gload16(src + l0 + 2 * dw, (void*)&Ws[buf][c * 256]);
        }
    };

    float xa[8], xb8[8];
    auto LOADX = [&](float* dst, int l0) {
        #pragma unroll
        for (int k = 0; k < 8; ++k)
            dst[k] = xg[(size_t)(l0 + k) * Dd];
    };

    f32x4 a0[6], a1[6];
    #pragma unroll
    for (int m = 0; m < 6; ++m) {
        a0[m] = (f32x4){0.f, 0.f, 0.f, 0.f};
        a1[m] = (f32x4){0.f, 0.f, 0.f, 0.f};
    }

    const int wdw = (4 * quad) ^ ((r16 & 3) << 2);  // Ws read swizzle (R3)

    union UF { u32x4 q; bf16x8 v; unsigned u[4]; };

    auto COMPUTE = [&](int buf, const float* xv) {
        UF xf;
        #pragma unroll
        for (int k2 = 0; k2 < 4; ++k2)
            xf.u[k2] = (unsigned)f2bf(xv[2 * k2]) |
                       ((unsigned)f2bf(xv[2 * k2 + 1]) << 16);
        #pragma unroll
        for (int m = 0; m < 6; ++m) {
            UF f0, f1;
            f0.q = *(const u32x4*)&Ws[buf][(16 * m + r16) * 16 + wdw];
            f1.q = *(const u32x4*)&Ws[buf][(96 + 16 * m + r16) * 16 + wdw];
            a0[m] = __builtin_amdgcn_mfma_f32_16x16x32_bf16(f0.v, xf.v, a0[m], 0, 0, 0);
            a1[m] = __builtin_amdgcn_mfma_f32_16x16x32_bf16(f1.v, xf.v, a1[m], 0, 0, 0);
        }
    };

    STAGE_W(0, 0);
    LOADX(xa, 0);
    __syncthreads();

    #pragma unroll
    for (int t = 0; t < 10; t += 2) {
        // phase A: tile t (even) in Ws[0] / xa; prefetch tile t+1
        STAGE_W(1, 32 * (t + 1));
        LOADX(xb8, 32 * (t + 1));
        COMPUTE(0, xa);
        __syncthreads();
        // phase B: tile t+1 (odd) in Ws[1] / xb8; prefetch tile t+2
        if (t + 2 < 10) {
            STAGE_W(0, 32 * (t + 2));
            LOADX(xa, 32 * (t + 2));
        }
        COMPUTE(1, xb8);
        __syncthreads();
    }

    // epilogue: fp32 combine + bias. C/D layout: col(d)=r16, row(p)=4*quad+reg
    const float* eb0 = expert_b + (size_t)e0 * Pp * Dd;
    const float* eb1 = expert_b + (size_t)e1 * Pp * Dd;
    #pragma unroll
    for (int m = 0; m < 6; ++m) {
        #pragma unroll
        for (int r = 0; r < 4; ++r) {
            const int p = 16 * m + 4 * quad + r;
            out[((size_t)b * Pp + p) * Dd + d] =
                g0 * (a0[m][r] + eb0[p * Dd + d]) +
                g1 * (a1[m][r] + eb1[p * Dd + d]);
        }
    }
}

extern "C" void kernel_launch(void* const* d_in, const int* in_sizes, int n_in,
                              void* d_out, int out_size, void* d_ws, size_t ws_size,
                              hipStream_t stream)
{
    const float* x        = (const float*)d_in[0];
    // d_in[1] = x_mark_enc (unused)
    const float* noise    = (const float*)d_in[2];
    const float* start_w  = (const float*)d_in[3];
    const float* start_b  = (const float*)d_in[4];
    const float* w_gate   = (const float*)d_in[5];
    const float* w_noise  = (const float*)d_in[6];
    const float* expert_w = (const float*)d_in[7];
    const float* expert_b = (const float*)d_in[8];
    float* out            = (float*)d_out;

    float* accum = (float*)d_ws;                 // 16 f
    float* gates = accum + 16;                   // 8192 f
    float* gbuf  = gates + Bn * Ee;              // 1024*320 f
    u16*   wt    = (u16*)(gbuf + Bn * Lr);       // 8*96*320 bf16

    hipLaunchKernelGGL(transpose_w, dim3(Ee, Lr / 32), dim3(256), 0, stream,
                       expert_w, wt, accum);
    hipLaunchKernelGGL(g_kernel, dim3(5, Bn), dim3(256), 0, stream,
                       x, start_w, start_b, gbuf);
    hipLaunchKernelGGL(gate_kernel, dim3(Bn / 4), dim3(256), 0, stream,
                       gbuf, noise, w_gate, w_noise, accum, gates);
    hipLaunchKernelGGL(mm_kernel, dim3(Bn * 2), dim3(256), 0, stream,
                       x, wt, expert_b, gates, accum, out);
}